// Round 14
// baseline (682.130 us; speedup 1.0000x reference)
//
#include <hip/hip_runtime.h>
#include <hip/hip_bf16.h>
#include <hip/hip_fp16.h>
#include <math.h>

#define H_DIM   128
#define NF_DIM  128
#define G_DIM   50
#define L_LAYERS 6
#define TBL     4096       // nearest-neighbor grid; h/2/sigma ~ 0.77% rel err
#define DMAX    12.8f
#define CUTOFF_C 10.0f
#define COEFF_C (-0.5f * 49.0f * 49.0f / 100.0f)
#define SCAN_B  256
#define T_PER   16
#define STG_STR 140

typedef __bf16 bf16x8 __attribute__((ext_vector_type(8)));
typedef float  f32x4  __attribute__((ext_vector_type(4)));

__device__ __forceinline__ float sspf(float x) {
    float e = __expf(-fabsf(x));
    return fmaxf(x, 0.0f) + __logf(1.0f + e) - 0.69314718055994530942f;
}

__device__ __forceinline__ unsigned short f2bf(float f) {
    unsigned int u = __float_as_uint(f);
    u = (u + 0x7fffu + ((u >> 16) & 1u)) >> 16;   // RNE
    return (unsigned short)u;
}

__device__ __forceinline__ float bf2f(unsigned short u) {
    return __uint_as_float(((unsigned int)u) << 16);
}

// XOR bank-swizzle for 16B A-frag chunks (c < 1024)
__device__ __forceinline__ int swz(int c) {
    return c ^ ((c >> 3) & 7) ^ ((c >> 8) & 3);
}

// ---------------------------------------------------------------- table phase 1
// syb[l][t][f] = bf16( ssp( g(d_t) @ W1[l] + b1[l] ) )
__global__ __launch_bounds__(128) void bt_sy(
        const float* __restrict__ w1, const float* __restrict__ b1,
        unsigned short* __restrict__ syb) {
    int l  = blockIdx.x / (TBL / T_PER);
    int t0 = (blockIdx.x % (TBL / T_PER)) * T_PER;
    int f  = threadIdx.x;  // 128
    __shared__ float sW1[G_DIM * 128];
    __shared__ float gs[T_PER][G_DIM + 2];
    for (int i = f; i < G_DIM * 128; i += 128)
        sW1[i] = w1[(size_t)l * G_DIM * 128 + i];
    if (f < G_DIM) {
        float o = f * (CUTOFF_C / (G_DIM - 1));
#pragma unroll
        for (int u = 0; u < T_PER; ++u) {
            float dt = (t0 + u) * (DMAX / (TBL - 1));
            float dd = dt - o;
            gs[u][f] = __expf(COEFF_C * dd * dd);
        }
    }
    __syncthreads();
    float y[T_PER];
    float bb = b1[l * 128 + f];
#pragma unroll
    for (int u = 0; u < T_PER; ++u) y[u] = bb;
    for (int g = 0; g < G_DIM; ++g) {
        float wv = sW1[g * 128 + f];
#pragma unroll
        for (int u = 0; u < T_PER; ++u) y[u] += gs[u][g] * wv;
    }
#pragma unroll
    for (int u = 0; u < T_PER; ++u)
        syb[((size_t)l * TBL + t0 + u) * 128 + f] = f2bf(sspf(y[u]));
}

// ---------------------------------------------------------------- table phase 2
// tabb[l][t][:] = syb[l][t][:] @ W2[l] + b2[l]   (MFMA)
__global__ __launch_bounds__(256, 4) void bt_gemm(
        const unsigned short* __restrict__ syb, const unsigned short* __restrict__ w2sw,
        const float* __restrict__ b2, unsigned short* __restrict__ tabb) {
    int l  = blockIdx.x >> 6;
    int m0 = (blockIdx.x & 63) * 64;
    const unsigned short* A = syb + (size_t)l * TBL * 128;
    const unsigned short* Bsw = w2sw + (size_t)l * 16384;
    const float* bias = b2 + l * 128;
    unsigned short* outp = tabb + (size_t)l * TBL * 128;

    __shared__ __align__(16) unsigned short frag[8192];
    __shared__ __align__(16) unsigned short stg[64 * STG_STR];
    int tid = threadIdx.x;
    for (int i = tid; i < 1024; i += 256) {
        int ks = i >> 8, w_ = (i >> 6) & 3, ln_ = i & 63;
        int row = m0 + w_ * 16 + (ln_ & 15);
        int kb = ks * 32 + (ln_ >> 4) * 8;
        uint4 v = *(const uint4*)(A + (size_t)row * 128 + kb);
        *(uint4*)(frag + swz(i) * 8) = v;
    }
    __syncthreads();
    int w = tid >> 6, ln = tid & 63;
    int quad = ln >> 4, l15 = ln & 15;
    f32x4 acc[8] = {};
#pragma unroll
    for (int ks = 0; ks < 4; ++ks) {
        bf16x8 af = *(const bf16x8*)(frag + swz((ks * 4 + w) * 64 + ln) * 8);
#pragma unroll
        for (int j = 0; j < 8; ++j) {
            bf16x8 bf = *(const bf16x8*)(Bsw + (((ks * 8 + j) * 64) + ln) * 8);
            acc[j] = __builtin_amdgcn_mfma_f32_16x16x32_bf16(af, bf, acc[j], 0, 0, 0);
        }
    }
#pragma unroll
    for (int j = 0; j < 8; ++j) {
        int col = j * 16 + l15;
        float bv = bias[col];
#pragma unroll
        for (int r = 0; r < 4; ++r)
            stg[(w * 16 + quad * 4 + r) * STG_STR + col] = f2bf(acc[j][r] + bv);
    }
    __syncthreads();
    for (int i = tid; i < 2048; i += 256) {
        int row = i >> 5, c4 = (i & 31) * 4;
        ushort4 s4 = *(const ushort4*)(stg + row * STG_STR + c4);
        *(uint2*)(outp + (size_t)(m0 + row) * 128 + c4) = *(const uint2*)&s4;
    }
}

// ---------------------------------------------------------------- embedding (bf16 h)
__global__ __launch_bounds__(256) void embed_kernel(
        const int* __restrict__ z, const float* __restrict__ emb,
        unsigned short* __restrict__ hb, int N) {
    int idx = blockIdx.x * blockDim.x + threadIdx.x;
    if (idx >= N * H_DIM) return;
    int n = idx >> 7, f = idx & 127;
    hb[idx] = f2bf(emb[z[n] * H_DIM + f]);
}

// ---------------------------------------------------------------- weight prep (25)
__global__ __launch_bounds__(256) void prep_wt_all(
        const float* __restrict__ c1w, const float* __restrict__ c2w,
        const float* __restrict__ iw, const float* __restrict__ l1w,
        const float* __restrict__ w2, unsigned short* __restrict__ Bsw) {
    int m = blockIdx.x;   // 0..24
    const float* src = (m < 6)  ? c1w + (size_t)m * 16384
                     : (m < 12) ? c2w + (size_t)(m - 6) * 16384
                     : (m < 18) ? iw  + (size_t)(m - 12) * 16384
                     : (m == 18) ? l1w
                                 : w2 + (size_t)(m - 19) * 16384;
    unsigned short* dst = Bsw + (size_t)m * 16384;
    for (int i = threadIdx.x; i < 16384; i += 256) {
        int jj = i & 7, lane = (i >> 3) & 63, j = (i >> 9) & 7, ks = i >> 12;
        int n = j * 16 + (lane & 15);
        int k = ks * 32 + ((lane >> 4) & 3) * 8 + jj;
        dst[i] = f2bf(src[k * 128 + n]);
    }
}

// ---------------------------------------------------------------- CSR build
__global__ __launch_bounds__(256) void count_kernel(
        const int* __restrict__ ec, int* __restrict__ cnt,
        int* __restrict__ rank, int E) {
    int e = blockIdx.x * blockDim.x + threadIdx.x;
    if (e < E) rank[e] = atomicAdd(&cnt[ec[e]], 1);
}

__global__ __launch_bounds__(SCAN_B) void scan1(
        const int* __restrict__ cnt, int* __restrict__ excl,
        int* __restrict__ bsums, int N) {
    __shared__ int s[SCAN_B];
    int i = blockIdx.x * SCAN_B + threadIdx.x;
    int v = (i < N) ? cnt[i] : 0;
    s[threadIdx.x] = v;
    __syncthreads();
    for (int off = 1; off < SCAN_B; off <<= 1) {
        int t = (threadIdx.x >= off) ? s[threadIdx.x - off] : 0;
        __syncthreads();
        s[threadIdx.x] += t;
        __syncthreads();
    }
    if (i < N) excl[i] = s[threadIdx.x] - v;
    if (threadIdx.x == SCAN_B - 1) bsums[blockIdx.x] = s[SCAN_B - 1];
}

__global__ __launch_bounds__(SCAN_B) void scan2(int* __restrict__ bsums, int nb) {
    __shared__ int s[SCAN_B];
    int v = (threadIdx.x < nb) ? bsums[threadIdx.x] : 0;
    s[threadIdx.x] = v;
    __syncthreads();
    for (int off = 1; off < SCAN_B; off <<= 1) {
        int t = (threadIdx.x >= off) ? s[threadIdx.x - off] : 0;
        __syncthreads();
        s[threadIdx.x] += t;
        __syncthreads();
    }
    if (threadIdx.x < nb) bsums[threadIdx.x] = s[threadIdx.x] - v;
}

__global__ __launch_bounds__(SCAN_B) void scan3(
        const int* __restrict__ excl, const int* __restrict__ bsums,
        int* __restrict__ row_start, int N, int E) {
    int i = blockIdx.x * SCAN_B + threadIdx.x;
    if (i < N) row_start[i] = excl[i] + bsums[blockIdx.x];
    if (i == 0) row_start[N] = E;
}

// 8-byte edge record {row|(i0<<17), fp32 C}; slot = row_start[col]+rank[e]
__global__ __launch_bounds__(256) void build_edges(
        const int* __restrict__ er, const int* __restrict__ ec,
        const float* __restrict__ pos, const int* __restrict__ row_start,
        const int* __restrict__ rank, uint2* __restrict__ ebuf, int E) {
    int e = blockIdx.x * blockDim.x + threadIdx.x;
    if (e >= E) return;
    int r = er[e], c = ec[e];
    float dx = pos[r * 3 + 0] - pos[c * 3 + 0];
    float dy = pos[r * 3 + 1] - pos[c * 3 + 1];
    float dz = pos[r * 3 + 2] - pos[c * 3 + 2];
    float d = sqrtf(dx * dx + dy * dy + dz * dz);
    float C = 0.5f * (cosf(d * (3.14159265358979323846f / CUTOFF_C)) + 1.0f);
    float t = fminf(d, DMAX) * ((TBL - 1) / DMAX);
    int i0 = (int)(t + 0.5f);
    if (i0 > TBL - 1) i0 = TBL - 1;
    ebuf[row_start[c] + rank[e]] =
        make_uint2((unsigned)r | ((unsigned)i0 << 17), __float_as_uint(C));
}

// ---------------------------------------------------------------- edge gather
__device__ __forceinline__ void edge_acc(
        unsigned ex, unsigned ey, const unsigned short* __restrict__ tabb,
        const unsigned short* __restrict__ xfb, int f4, float4& acc) {
    int r = ex & 0x1ffff, i0 = ex >> 17;
    float C = __uint_as_float(ey);
    const ushort4 tw = *(const ushort4*)(tabb + (size_t)i0 * 128 + f4);
    const ushort4 xu = *(const ushort4*)(xfb + (size_t)r * 128 + f4);
    acc.x = fmaf(bf2f(xu.x) * bf2f(tw.x), C, acc.x);
    acc.y = fmaf(bf2f(xu.y) * bf2f(tw.y), C, acc.y);
    acc.z = fmaf(bf2f(xu.z) * bf2f(tw.z), C, acc.z);
    acc.w = fmaf(bf2f(xu.w) * bf2f(tw.w), C, acc.w);
}

// 32 lanes/atom, 4 edges in flight
__global__ __launch_bounds__(256) void edge_agg(
        const uint2* __restrict__ ebuf, const int* __restrict__ row_start,
        const unsigned short* __restrict__ xfb, const unsigned short* __restrict__ tabb,
        unsigned short* __restrict__ aggb, int N) {
    int tid = threadIdx.x;
    int atom = blockIdx.x * 8 + (tid >> 5);
    if (atom >= N) return;
    int f4 = (tid & 31) * 4;
    float4 a0 = make_float4(0.f, 0.f, 0.f, 0.f);
    float4 a1 = make_float4(0.f, 0.f, 0.f, 0.f);
    float4 a2 = make_float4(0.f, 0.f, 0.f, 0.f);
    float4 a3 = make_float4(0.f, 0.f, 0.f, 0.f);
    int j0 = row_start[atom], j1 = row_start[atom + 1];
    int j = j0;
    if (j < j1 && (j & 1)) {
        uint2 ed = ebuf[j];
        edge_acc(ed.x, ed.y, tabb, xfb, f4, a0);
        ++j;
    }
    for (; j + 3 < j1; j += 4) {
        uint4 e0 = *(const uint4*)(ebuf + j);
        uint4 e1 = *(const uint4*)(ebuf + j + 2);
        edge_acc(e0.x, e0.y, tabb, xfb, f4, a0);
        edge_acc(e0.z, e0.w, tabb, xfb, f4, a1);
        edge_acc(e1.x, e1.y, tabb, xfb, f4, a2);
        edge_acc(e1.z, e1.w, tabb, xfb, f4, a3);
    }
    if (j + 1 < j1) {
        uint4 e0 = *(const uint4*)(ebuf + j);
        edge_acc(e0.x, e0.y, tabb, xfb, f4, a0);
        edge_acc(e0.z, e0.w, tabb, xfb, f4, a1);
        j += 2;
    }
    if (j < j1) {
        uint2 ed = ebuf[j];
        edge_acc(ed.x, ed.y, tabb, xfb, f4, a0);
    }
    a0.x += a1.x + a2.x + a3.x;
    a0.y += a1.y + a2.y + a3.y;
    a0.z += a1.z + a2.z + a3.z;
    a0.w += a1.w + a2.w + a3.w;
    unsigned short o[4] = {f2bf(a0.x), f2bf(a0.y), f2bf(a0.z), f2bf(a0.w)};
    *(uint2*)(aggb + (size_t)atom * 128 + f4) = *(const uint2*)o;
}

// ---------------------------------------------------------------- layer-0 GEMM
__global__ __launch_bounds__(256, 4) void gemm_l0(
        const unsigned short* __restrict__ hb, const unsigned short* __restrict__ Bsw,
        unsigned short* __restrict__ xfb, int M) {
    __shared__ __align__(16) unsigned short frag[8192];
    __shared__ __align__(16) unsigned short stg[64 * STG_STR];
    int tid = threadIdx.x;
    int m0 = blockIdx.x * 64;
    for (int i = tid; i < 1024; i += 256) {
        int ks = i >> 8, w_ = (i >> 6) & 3, ln_ = i & 63;
        int row = m0 + w_ * 16 + (ln_ & 15);
        int kb = ks * 32 + (ln_ >> 4) * 8;
        uint4 v = make_uint4(0, 0, 0, 0);
        if (row < M) v = *(const uint4*)(hb + (size_t)row * 128 + kb);
        *(uint4*)(frag + swz(i) * 8) = v;
    }
    __syncthreads();
    int w = tid >> 6, ln = tid & 63;
    int quad = ln >> 4, l15 = ln & 15;
    f32x4 acc[8] = {};
#pragma unroll
    for (int ks = 0; ks < 4; ++ks) {
        bf16x8 af = *(const bf16x8*)(frag + swz((ks * 4 + w) * 64 + ln) * 8);
#pragma unroll
        for (int j = 0; j < 8; ++j) {
            bf16x8 bf = *(const bf16x8*)(Bsw + (((ks * 8 + j) * 64) + ln) * 8);
            acc[j] = __builtin_amdgcn_mfma_f32_16x16x32_bf16(af, bf, acc[j], 0, 0, 0);
        }
    }
#pragma unroll
    for (int j = 0; j < 8; ++j) {
        int col = j * 16 + l15;
#pragma unroll
        for (int r = 0; r < 4; ++r)
            stg[(w * 16 + quad * 4 + r) * STG_STR + col] = f2bf(acc[j][r]);
    }
    __syncthreads();
    for (int i = tid; i < 2048; i += 256) {
        int row = i >> 5, c4 = (i & 31) * 4;
        int grow = m0 + row;
        if (grow >= M) continue;
        ushort4 s4 = *(const ushort4*)(stg + row * STG_STR + c4);
        *(uint2*)(xfb + (size_t)grow * 128 + c4) = *(const uint2*)&s4;
    }
}

// ---------------------------------------------------------------- fused layer (r12 + h-prefetch)
// t1 = aggb@c2w+c2b; x = ssp(t1)@iw+ib; h += x (bf16 h, prefetched);
// out = bf16(h@B3) (mid) or bf16(ssp(h@B3+b3)) (last) -> xfb_out.
__global__ __launch_bounds__(256, 4) void fused_layer(
        const unsigned short* __restrict__ aggb,
        const unsigned short* __restrict__ B1sw, const float* __restrict__ b1v,
        const unsigned short* __restrict__ B2sw, const float* __restrict__ b2v,
        const unsigned short* __restrict__ B3sw, const float* __restrict__ b3v,
        unsigned short* __restrict__ hb, unsigned short* __restrict__ xfb_out,
        int M, int last) {
    __shared__ __align__(16) unsigned short frag[8192];         // 16 KB
    __shared__ __align__(16) unsigned short stg[64 * STG_STR];  // 17.5 KB
    int tid = threadIdx.x;
    int m0 = blockIdx.x * 64;

    // stage aggb rows -> swizzled A-frags
    for (int i = tid; i < 1024; i += 256) {
        int ks = i >> 8, w_ = (i >> 6) & 3, ln_ = i & 63;
        int row = m0 + w_ * 16 + (ln_ & 15);
        int kb = ks * 32 + (ln_ >> 4) * 8;
        uint4 v = make_uint4(0, 0, 0, 0);
        if (row < M) v = *(const uint4*)(aggb + (size_t)row * 128 + kb);
        *(uint4*)(frag + swz(i) * 8) = v;
    }

    // prefetch h rows (consumed after int_lin; latency hides behind MFMA phases)
    uint2 hpre[8];
#pragma unroll
    for (int it = 0; it < 8; ++it) {
        int i = tid + it * 256;
        int row = i >> 5, c4 = (i & 31) * 4;
        int grow = m0 + row;
        hpre[it] = (grow < M) ? *(const uint2*)(hb + (size_t)grow * 128 + c4)
                              : make_uint2(0u, 0u);
    }
    __syncthreads();

    int w = tid >> 6, ln = tid & 63;
    int quad = ln >> 4, l15 = ln & 15;

    // conv2 MFMA
    f32x4 acc[8] = {};
#pragma unroll
    for (int ks = 0; ks < 4; ++ks) {
        bf16x8 af = *(const bf16x8*)(frag + swz((ks * 4 + w) * 64 + ln) * 8);
#pragma unroll
        for (int j = 0; j < 8; ++j) {
            bf16x8 bf = *(const bf16x8*)(B1sw + (((ks * 8 + j) * 64) + ln) * 8);
            acc[j] = __builtin_amdgcn_mfma_f32_16x16x32_bf16(af, bf, acc[j], 0, 0, 0);
        }
    }

    // repack ssp(t1+b1) -> A-frags (own-wave chunks; intra-wave ds ordering)
#pragma unroll
    for (int j = 0; j < 8; ++j) {
        int col = j * 16 + l15;
        float bv = b1v[col];
        int ks2 = j >> 1;
        int quad2 = (col >> 3) & 3;
        int jj = l15 & 7;
        int cbase = (ks2 * 4 + w) * 64 + quad2 * 16 + quad * 4;
#pragma unroll
        for (int r = 0; r < 4; ++r) {
            float s = sspf(acc[j][r] + bv);
            frag[swz(cbase + r) * 8 + jj] = f2bf(s);
        }
    }

    // int_lin MFMA
    f32x4 acc2[8] = {};
#pragma unroll
    for (int ks = 0; ks < 4; ++ks) {
        bf16x8 af = *(const bf16x8*)(frag + swz((ks * 4 + w) * 64 + ln) * 8);
#pragma unroll
        for (int j = 0; j < 8; ++j) {
            bf16x8 bf = *(const bf16x8*)(B2sw + (((ks * 8 + j) * 64) + ln) * 8);
            acc2[j] = __builtin_amdgcn_mfma_f32_16x16x32_bf16(af, bf, acc2[j], 0, 0, 0);
        }
    }

    // stage x = bf16(acc2 + b2)
#pragma unroll
    for (int j = 0; j < 8; ++j) {
        int col = j * 16 + l15;
        float bv = b2v[col];
#pragma unroll
        for (int r = 0; r < 4; ++r)
            stg[(w * 16 + quad * 4 + r) * STG_STR + col] = f2bf(acc2[j][r] + bv);
    }
    __syncthreads();

    // h += x using prefetched h; write h_new to global + frag LDS
#pragma unroll
    for (int it = 0; it < 8; ++it) {
        int i = tid + it * 256;
        int row = i >> 5, c4 = (i & 31) * 4;
        int grow = m0 + row;
        ushort4 xv = *(const ushort4*)(stg + row * STG_STR + c4);
        unsigned short t4[4];
        if (grow < M) {
            ushort4 hv = *(const ushort4*)&hpre[it];
            t4[0] = f2bf(bf2f(hv.x) + bf2f(xv.x));
            t4[1] = f2bf(bf2f(hv.y) + bf2f(xv.y));
            t4[2] = f2bf(bf2f(hv.z) + bf2f(xv.z));
            t4[3] = f2bf(bf2f(hv.w) + bf2f(xv.w));
            *(uint2*)(hb + (size_t)grow * 128 + c4) = *(const uint2*)t4;
        } else {
            t4[0] = t4[1] = t4[2] = t4[3] = 0;
        }
        int w_ = row >> 4, l15_ = row & 15;
        int ks = c4 >> 5, q_ = (c4 >> 3) & 3, jj = c4 & 7;
        int c = (ks * 4 + w_) * 64 + q_ * 16 + l15_;
        *(uint2*)(frag + swz(c) * 8 + jj) = *(const uint2*)t4;
    }
    __syncthreads();

    // next conv1 (or lin1) MFMA
    f32x4 acc3[8] = {};
#pragma unroll
    for (int ks = 0; ks < 4; ++ks) {
        bf16x8 af = *(const bf16x8*)(frag + swz((ks * 4 + w) * 64 + ln) * 8);
#pragma unroll
        for (int j = 0; j < 8; ++j) {
            bf16x8 bf = *(const bf16x8*)(B3sw + (((ks * 8 + j) * 64) + ln) * 8);
            acc3[j] = __builtin_amdgcn_mfma_f32_16x16x32_bf16(af, bf, acc3[j], 0, 0, 0);
        }
    }

    // stage output bf16 (ssp in fp32 before rounding on last layer)
#pragma unroll
    for (int j = 0; j < 8; ++j) {
        int col = j * 16 + l15;
        float bv = last ? b3v[col] : 0.f;
#pragma unroll
        for (int r = 0; r < 4; ++r) {
            float v = acc3[j][r] + bv;
            if (last) v = sspf(v);
            stg[(w * 16 + quad * 4 + r) * STG_STR + col] = f2bf(v);
        }
    }
    __syncthreads();

    // write xfb_out (bf16; last layer this is s)
    for (int i = tid; i < 2048; i += 256) {
        int row = i >> 5, c4 = (i & 31) * 4;
        int grow = m0 + row;
        if (grow >= M) continue;
        ushort4 s4 = *(const ushort4*)(stg + row * STG_STR + c4);
        *(uint2*)(xfb_out + (size_t)grow * 128 + c4) = *(const uint2*)&s4;
    }
}

// ---------------------------------------------------------------- atom -> mol sum (bf16 in)
#define MR_ATOMS 32
__global__ __launch_bounds__(128) void mol_reduce(
        const unsigned short* __restrict__ s, const int* __restrict__ a2c,
        const int* __restrict__ c2m, float* __restrict__ mols,
        int* __restrict__ cnt, int N) {
    int f = threadIdx.x;
    int a0 = blockIdx.x * MR_ATOMS;
    int a1 = min(a0 + MR_ATOMS, N);
    float sum = 0.f;
    int cur = -1, run = 0;
    for (int a = a0; a < a1; ++a) {
        int m = c2m[a2c[a]];
        if (m != cur) {
            if (cur >= 0) {
                unsafeAtomicAdd(&mols[(size_t)cur * H_DIM + f], sum);
                if (f == 0) atomicAdd(&cnt[cur], run);
            }
            cur = m; sum = 0.f; run = 0;
        }
        sum += bf2f(s[(size_t)a * H_DIM + f]);
        ++run;
    }
    if (cur >= 0) {
        unsafeAtomicAdd(&mols[(size_t)cur * H_DIM + f], sum);
        if (f == 0) atomicAdd(&cnt[cur], run);
    }
}

// ---------------------------------------------------------------- head
__global__ __launch_bounds__(128) void head_kernel(
        const float* __restrict__ mols, const int* __restrict__ cnt,
        const float* __restrict__ l2w, const float* __restrict__ l2b,
        const float* __restrict__ hw1, const float* __restrict__ hb1,
        const float* __restrict__ hw2, const float* __restrict__ hb2,
        float* __restrict__ out) {
    int m = blockIdx.x, f = threadIdx.x;
    __shared__ float me[H_DIM];
    __shared__ float u[H_DIM / 2];
    const float* ms = mols + (size_t)m * H_DIM;
    float acc = l2b[f] * (float)cnt[m];
#pragma unroll 16
    for (int k = 0; k < H_DIM; ++k) acc += ms[k] * l2w[k * H_DIM + f];
    me[f] = acc;
    __syncthreads();
    if (f < 64) {
        float a2 = hb1[f];
#pragma unroll 16
        for (int k = 0; k < H_DIM; ++k) a2 += me[k] * hw1[k * 64 + f];
        u[f] = sspf(a2);
    }
    __syncthreads();
    if (f == 0) {
        float o = hb2[0];
#pragma unroll 16
        for (int j = 0; j < 64; ++j) o += u[j] * hw2[j];
        out[m] = o;
    }
}

// ---------------------------------------------------------------- launch
extern "C" void kernel_launch(void* const* d_in, const int* in_sizes, int n_in,
                              void* d_out, int out_size, void* d_ws, size_t ws_size,
                              hipStream_t stream) {
    const int*   z   = (const int*)d_in[0];
    const float* pos = (const float*)d_in[1];
    const int*   er  = (const int*)d_in[2];
    const int*   ec  = (const int*)d_in[3];
    const int*   a2c = (const int*)d_in[4];
    const int*   c2m = (const int*)d_in[5];
    const float* emb = (const float*)d_in[6];
    const float* w1  = (const float*)d_in[7];
    const float* b1  = (const float*)d_in[8];
    const float* w2  = (const float*)d_in[9];
    const float* b2  = (const float*)d_in[10];
    const float* c1w = (const float*)d_in[11];
    const float* c2w = (const float*)d_in[12];
    const float* c2b = (const float*)d_in[13];
    const float* iw  = (const float*)d_in[14];
    const float* ib  = (const float*)d_in[15];
    const float* l1w = (const float*)d_in[16];
    const float* l1b = (const float*)d_in[17];
    const float* l2w = (const float*)d_in[18];
    const float* l2b = (const float*)d_in[19];
    const float* hw1 = (const float*)d_in[20];
    const float* hb1 = (const float*)d_in[21];
    const float* hw2 = (const float*)d_in[22];
    const float* hb2 = (const float*)d_in[23];

    const int N  = in_sizes[0];
    const int E  = in_sizes[2];
    const int NM = out_size;
    float* out = (float*)d_out;

    // workspace layout (~70 MB)
    char* wsp = (char*)d_ws;
    uint2* ebuf = (uint2*)wsp;            wsp += (size_t)E * 8;
    unsigned short* tabb = (unsigned short*)wsp;  wsp += (size_t)L_LAYERS * TBL * NF_DIM * 2;
    unsigned short* syb  = (unsigned short*)wsp;  wsp += (size_t)L_LAYERS * TBL * NF_DIM * 2;
    unsigned short* wbt = (unsigned short*)wsp;  wsp += (size_t)25 * 16384 * 2;
    unsigned short* hb  = (unsigned short*)wsp;  wsp += (size_t)N * H_DIM * 2;
    unsigned short* xfb = (unsigned short*)wsp;  wsp += (size_t)N * H_DIM * 2;
    unsigned short* aggb = (unsigned short*)wsp; wsp += (size_t)N * H_DIM * 2;
    float* mols = (float*)wsp;            wsp += (size_t)NM * H_DIM * 4;
    int*   cnt_m = (int*)wsp;             wsp += (size_t)NM * 4;
    int*   ccnt  = (int*)wsp;             wsp += (size_t)N * 4;
    int*   row_start = (int*)wsp;         wsp += (size_t)(N + 1) * 4;
    int*   rank  = (int*)wsp;             wsp += (size_t)E * 4;
    int*   bsums = (int*)wsp;             wsp += 256 * 4;
    int*   excl  = (int*)wsp;

    // --- CSR build (rank-based, atomic-free scatter) ---
    hipMemsetAsync(ccnt, 0, (size_t)N * sizeof(int), stream);
    count_kernel<<<(E + 255) / 256, 256, 0, stream>>>(ec, ccnt, rank, E);
    int nb = (N + SCAN_B - 1) / SCAN_B;
    scan1<<<nb, SCAN_B, 0, stream>>>(ccnt, excl, bsums, N);
    scan2<<<1, SCAN_B, 0, stream>>>(bsums, nb);
    scan3<<<nb, SCAN_B, 0, stream>>>(excl, bsums, row_start, N, E);
    build_edges<<<(E + 255) / 256, 256, 0, stream>>>(
        er, ec, pos, row_start, rank, ebuf, E);

    // --- filter tables: VALU phase then MFMA phase ---
    bt_sy<<<L_LAYERS * (TBL / T_PER), 128, 0, stream>>>(w1, b1, syb);
    embed_kernel<<<(N * H_DIM + 255) / 256, 256, 0, stream>>>(z, emb, hb, N);
    prep_wt_all<<<25, 256, 0, stream>>>(c1w, c2w, iw, l1w, w2, wbt);
    bt_gemm<<<L_LAYERS * (TBL / 64), 256, 0, stream>>>(
        syb, wbt + (size_t)19 * 16384, b2, tabb);

    int gblocks = (N + 63) / 64;
    gemm_l0<<<gblocks, 256, 0, stream>>>(hb, wbt, xfb, N);

    for (int l = 0; l < L_LAYERS; ++l) {
        edge_agg<<<(N + 7) / 8, 256, 0, stream>>>(
            ebuf, row_start, xfb, tabb + (size_t)l * TBL * NF_DIM, aggb, N);
        int last = (l == L_LAYERS - 1);
        const unsigned short* B3 = last ? wbt + (size_t)18 * 16384
                                        : wbt + (size_t)(l + 1) * 16384;
        fused_layer<<<gblocks, 256, 0, stream>>>(
            aggb,
            wbt + (size_t)(6 + l) * 16384,  c2b + (size_t)l * H_DIM,
            wbt + (size_t)(12 + l) * 16384, ib + (size_t)l * H_DIM,
            B3, l1b, hb, xfb, N, last);
    }
    // final s (bf16) is in xfb

    hipMemsetAsync(mols, 0, (size_t)NM * H_DIM * sizeof(float) + NM * sizeof(int), stream);
    mol_reduce<<<(N + MR_ATOMS - 1) / MR_ATOMS, 128, 0, stream>>>(
        xfb, a2c, c2m, mols, cnt_m, N);
    head_kernel<<<NM, 128, 0, stream>>>(mols, cnt_m, l2w, l2b, hw1, hb1, hw2, hb2, out);
}

// Round 15
// 622.684 us; speedup vs baseline: 1.0955x; 1.0955x over previous
//
#include <hip/hip_runtime.h>
#include <hip/hip_bf16.h>
#include <hip/hip_fp16.h>
#include <math.h>

#define H_DIM   128
#define NF_DIM  128
#define G_DIM   50
#define L_LAYERS 6
#define TBL     4096       // nearest-neighbor grid; h/2/sigma ~ 0.77% rel err
#define DMAX    12.8f
#define CUTOFF_C 10.0f
#define COEFF_C (-0.5f * 49.0f * 49.0f / 100.0f)
#define SCAN_B  256
#define T_PER   16
#define STG_STR 140

typedef __bf16 bf16x8 __attribute__((ext_vector_type(8)));
typedef float  f32x4  __attribute__((ext_vector_type(4)));

__device__ __forceinline__ float sspf(float x) {
    float e = __expf(-fabsf(x));
    return fmaxf(x, 0.0f) + __logf(1.0f + e) - 0.69314718055994530942f;
}

__device__ __forceinline__ unsigned short f2bf(float f) {
    unsigned int u = __float_as_uint(f);
    u = (u + 0x7fffu + ((u >> 16) & 1u)) >> 16;   // RNE
    return (unsigned short)u;
}

__device__ __forceinline__ float bf2f(unsigned short u) {
    return __uint_as_float(((unsigned int)u) << 16);
}

// XOR bank-swizzle for 16B A-frag chunks (c < 1024)
__device__ __forceinline__ int swz(int c) {
    return c ^ ((c >> 3) & 7) ^ ((c >> 8) & 3);
}

// ---------------------------------------------------------------- table phase 1
__global__ __launch_bounds__(128) void bt_sy(
        const float* __restrict__ w1, const float* __restrict__ b1,
        unsigned short* __restrict__ syb) {
    int l  = blockIdx.x / (TBL / T_PER);
    int t0 = (blockIdx.x % (TBL / T_PER)) * T_PER;
    int f  = threadIdx.x;  // 128
    __shared__ float sW1[G_DIM * 128];
    __shared__ float gs[T_PER][G_DIM + 2];
    for (int i = f; i < G_DIM * 128; i += 128)
        sW1[i] = w1[(size_t)l * G_DIM * 128 + i];
    if (f < G_DIM) {
        float o = f * (CUTOFF_C / (G_DIM - 1));
#pragma unroll
        for (int u = 0; u < T_PER; ++u) {
            float dt = (t0 + u) * (DMAX / (TBL - 1));
            float dd = dt - o;
            gs[u][f] = __expf(COEFF_C * dd * dd);
        }
    }
    __syncthreads();
    float y[T_PER];
    float bb = b1[l * 128 + f];
#pragma unroll
    for (int u = 0; u < T_PER; ++u) y[u] = bb;
    for (int g = 0; g < G_DIM; ++g) {
        float wv = sW1[g * 128 + f];
#pragma unroll
        for (int u = 0; u < T_PER; ++u) y[u] += gs[u][g] * wv;
    }
#pragma unroll
    for (int u = 0; u < T_PER; ++u)
        syb[((size_t)l * TBL + t0 + u) * 128 + f] = f2bf(sspf(y[u]));
}

// ---------------------------------------------------------------- table phase 2
__global__ __launch_bounds__(256, 4) void bt_gemm(
        const unsigned short* __restrict__ syb, const unsigned short* __restrict__ w2sw,
        const float* __restrict__ b2, unsigned short* __restrict__ tabb) {
    int l  = blockIdx.x >> 6;
    int m0 = (blockIdx.x & 63) * 64;
    const unsigned short* A = syb + (size_t)l * TBL * 128;
    const unsigned short* Bsw = w2sw + (size_t)l * 16384;
    const float* bias = b2 + l * 128;
    unsigned short* outp = tabb + (size_t)l * TBL * 128;

    __shared__ __align__(16) unsigned short frag[8192];
    __shared__ __align__(16) unsigned short stg[64 * STG_STR];
    int tid = threadIdx.x;
    for (int i = tid; i < 1024; i += 256) {
        int ks = i >> 8, w_ = (i >> 6) & 3, ln_ = i & 63;
        int row = m0 + w_ * 16 + (ln_ & 15);
        int kb = ks * 32 + (ln_ >> 4) * 8;
        uint4 v = *(const uint4*)(A + (size_t)row * 128 + kb);
        *(uint4*)(frag + swz(i) * 8) = v;
    }
    __syncthreads();
    int w = tid >> 6, ln = tid & 63;
    int quad = ln >> 4, l15 = ln & 15;
    f32x4 acc[8] = {};
#pragma unroll
    for (int ks = 0; ks < 4; ++ks) {
        bf16x8 af = *(const bf16x8*)(frag + swz((ks * 4 + w) * 64 + ln) * 8);
#pragma unroll
        for (int j = 0; j < 8; ++j) {
            bf16x8 bf = *(const bf16x8*)(Bsw + (((ks * 8 + j) * 64) + ln) * 8);
            acc[j] = __builtin_amdgcn_mfma_f32_16x16x32_bf16(af, bf, acc[j], 0, 0, 0);
        }
    }
#pragma unroll
    for (int j = 0; j < 8; ++j) {
        int col = j * 16 + l15;
        float bv = bias[col];
#pragma unroll
        for (int r = 0; r < 4; ++r)
            stg[(w * 16 + quad * 4 + r) * STG_STR + col] = f2bf(acc[j][r] + bv);
    }
    __syncthreads();
    for (int i = tid; i < 2048; i += 256) {
        int row = i >> 5, c4 = (i & 31) * 4;
        ushort4 s4 = *(const ushort4*)(stg + row * STG_STR + c4);
        *(uint2*)(outp + (size_t)(m0 + row) * 128 + c4) = *(const uint2*)&s4;
    }
}

// ---------------------------------------------------------------- embedding (bf16 h)
__global__ __launch_bounds__(256) void embed_kernel(
        const int* __restrict__ z, const float* __restrict__ emb,
        unsigned short* __restrict__ hb, int N) {
    int idx = blockIdx.x * blockDim.x + threadIdx.x;
    if (idx >= N * H_DIM) return;
    int n = idx >> 7, f = idx & 127;
    hb[idx] = f2bf(emb[z[n] * H_DIM + f]);
}

// ---------------------------------------------------------------- weight prep (25)
__global__ __launch_bounds__(256) void prep_wt_all(
        const float* __restrict__ c1w, const float* __restrict__ c2w,
        const float* __restrict__ iw, const float* __restrict__ l1w,
        const float* __restrict__ w2, unsigned short* __restrict__ Bsw) {
    int m = blockIdx.x;   // 0..24
    const float* src = (m < 6)  ? c1w + (size_t)m * 16384
                     : (m < 12) ? c2w + (size_t)(m - 6) * 16384
                     : (m < 18) ? iw  + (size_t)(m - 12) * 16384
                     : (m == 18) ? l1w
                                 : w2 + (size_t)(m - 19) * 16384;
    unsigned short* dst = Bsw + (size_t)m * 16384;
    for (int i = threadIdx.x; i < 16384; i += 256) {
        int jj = i & 7, lane = (i >> 3) & 63, j = (i >> 9) & 7, ks = i >> 12;
        int n = j * 16 + (lane & 15);
        int k = ks * 32 + ((lane >> 4) & 3) * 8 + jj;
        dst[i] = f2bf(src[k * 128 + n]);
    }
}

// ---------------------------------------------------------------- CSR build
__global__ __launch_bounds__(256) void count_kernel(
        const int* __restrict__ ec, int* __restrict__ cnt,
        int* __restrict__ rank, int E) {
    int e = blockIdx.x * blockDim.x + threadIdx.x;
    if (e < E) rank[e] = atomicAdd(&cnt[ec[e]], 1);
}

__global__ __launch_bounds__(SCAN_B) void scan1(
        const int* __restrict__ cnt, int* __restrict__ excl,
        int* __restrict__ bsums, int N) {
    __shared__ int s[SCAN_B];
    int i = blockIdx.x * SCAN_B + threadIdx.x;
    int v = (i < N) ? cnt[i] : 0;
    s[threadIdx.x] = v;
    __syncthreads();
    for (int off = 1; off < SCAN_B; off <<= 1) {
        int t = (threadIdx.x >= off) ? s[threadIdx.x - off] : 0;
        __syncthreads();
        s[threadIdx.x] += t;
        __syncthreads();
    }
    if (i < N) excl[i] = s[threadIdx.x] - v;
    if (threadIdx.x == SCAN_B - 1) bsums[blockIdx.x] = s[SCAN_B - 1];
}

__global__ __launch_bounds__(SCAN_B) void scan2(int* __restrict__ bsums, int nb) {
    __shared__ int s[SCAN_B];
    int v = (threadIdx.x < nb) ? bsums[threadIdx.x] : 0;
    s[threadIdx.x] = v;
    __syncthreads();
    for (int off = 1; off < SCAN_B; off <<= 1) {
        int t = (threadIdx.x >= off) ? s[threadIdx.x - off] : 0;
        __syncthreads();
        s[threadIdx.x] += t;
        __syncthreads();
    }
    if (threadIdx.x < nb) bsums[threadIdx.x] = s[threadIdx.x] - v;
}

__global__ __launch_bounds__(SCAN_B) void scan3(
        const int* __restrict__ excl, const int* __restrict__ bsums,
        int* __restrict__ row_start, int N, int E) {
    int i = blockIdx.x * SCAN_B + threadIdx.x;
    if (i < N) row_start[i] = excl[i] + bsums[blockIdx.x];
    if (i == 0) row_start[N] = E;
}

// 8-byte edge record {row|(i0<<17), fp32 C}; slot = row_start[col]+rank[e]
__global__ __launch_bounds__(256) void build_edges(
        const int* __restrict__ er, const int* __restrict__ ec,
        const float* __restrict__ pos, const int* __restrict__ row_start,
        const int* __restrict__ rank, uint2* __restrict__ ebuf, int E) {
    int e = blockIdx.x * blockDim.x + threadIdx.x;
    if (e >= E) return;
    int r = er[e], c = ec[e];
    float dx = pos[r * 3 + 0] - pos[c * 3 + 0];
    float dy = pos[r * 3 + 1] - pos[c * 3 + 1];
    float dz = pos[r * 3 + 2] - pos[c * 3 + 2];
    float d = sqrtf(dx * dx + dy * dy + dz * dz);
    float C = 0.5f * (cosf(d * (3.14159265358979323846f / CUTOFF_C)) + 1.0f);
    float t = fminf(d, DMAX) * ((TBL - 1) / DMAX);
    int i0 = (int)(t + 0.5f);
    if (i0 > TBL - 1) i0 = TBL - 1;
    ebuf[row_start[c] + rank[e]] =
        make_uint2((unsigned)r | ((unsigned)i0 << 17), __float_as_uint(C));
}

// ---------------------------------------------------------------- edge gather
__device__ __forceinline__ void edge_acc(
        unsigned ex, unsigned ey, const unsigned short* __restrict__ tabb,
        const unsigned short* __restrict__ xfb, int f4, float4& acc) {
    int r = ex & 0x1ffff, i0 = ex >> 17;
    float C = __uint_as_float(ey);
    const ushort4 tw = *(const ushort4*)(tabb + (size_t)i0 * 128 + f4);
    const ushort4 xu = *(const ushort4*)(xfb + (size_t)r * 128 + f4);
    acc.x = fmaf(bf2f(xu.x) * bf2f(tw.x), C, acc.x);
    acc.y = fmaf(bf2f(xu.y) * bf2f(tw.y), C, acc.y);
    acc.z = fmaf(bf2f(xu.z) * bf2f(tw.z), C, acc.z);
    acc.w = fmaf(bf2f(xu.w) * bf2f(tw.w), C, acc.w);
}

// 32 lanes/atom, 4 edges in flight
__global__ __launch_bounds__(256) void edge_agg(
        const uint2* __restrict__ ebuf, const int* __restrict__ row_start,
        const unsigned short* __restrict__ xfb, const unsigned short* __restrict__ tabb,
        unsigned short* __restrict__ aggb, int N) {
    int tid = threadIdx.x;
    int atom = blockIdx.x * 8 + (tid >> 5);
    if (atom >= N) return;
    int f4 = (tid & 31) * 4;
    float4 a0 = make_float4(0.f, 0.f, 0.f, 0.f);
    float4 a1 = make_float4(0.f, 0.f, 0.f, 0.f);
    float4 a2 = make_float4(0.f, 0.f, 0.f, 0.f);
    float4 a3 = make_float4(0.f, 0.f, 0.f, 0.f);
    int j0 = row_start[atom], j1 = row_start[atom + 1];
    int j = j0;
    if (j < j1 && (j & 1)) {
        uint2 ed = ebuf[j];
        edge_acc(ed.x, ed.y, tabb, xfb, f4, a0);
        ++j;
    }
    for (; j + 3 < j1; j += 4) {
        uint4 e0 = *(const uint4*)(ebuf + j);
        uint4 e1 = *(const uint4*)(ebuf + j + 2);
        edge_acc(e0.x, e0.y, tabb, xfb, f4, a0);
        edge_acc(e0.z, e0.w, tabb, xfb, f4, a1);
        edge_acc(e1.x, e1.y, tabb, xfb, f4, a2);
        edge_acc(e1.z, e1.w, tabb, xfb, f4, a3);
    }
    if (j + 1 < j1) {
        uint4 e0 = *(const uint4*)(ebuf + j);
        edge_acc(e0.x, e0.y, tabb, xfb, f4, a0);
        edge_acc(e0.z, e0.w, tabb, xfb, f4, a1);
        j += 2;
    }
    if (j < j1) {
        uint2 ed = ebuf[j];
        edge_acc(ed.x, ed.y, tabb, xfb, f4, a0);
    }
    a0.x += a1.x + a2.x + a3.x;
    a0.y += a1.y + a2.y + a3.y;
    a0.z += a1.z + a2.z + a3.z;
    a0.w += a1.w + a2.w + a3.w;
    unsigned short o[4] = {f2bf(a0.x), f2bf(a0.y), f2bf(a0.z), f2bf(a0.w)};
    *(uint2*)(aggb + (size_t)atom * 128 + f4) = *(const uint2*)o;
}

// ---------------------------------------------------------------- layer-0 GEMM
__global__ __launch_bounds__(256, 4) void gemm_l0(
        const unsigned short* __restrict__ hb, const unsigned short* __restrict__ Bsw,
        unsigned short* __restrict__ xfb, int M) {
    __shared__ __align__(16) unsigned short frag[8192];
    __shared__ __align__(16) unsigned short stg[64 * STG_STR];
    int tid = threadIdx.x;
    int m0 = blockIdx.x * 64;
    for (int i = tid; i < 1024; i += 256) {
        int ks = i >> 8, w_ = (i >> 6) & 3, ln_ = i & 63;
        int row = m0 + w_ * 16 + (ln_ & 15);
        int kb = ks * 32 + (ln_ >> 4) * 8;
        uint4 v = make_uint4(0, 0, 0, 0);
        if (row < M) v = *(const uint4*)(hb + (size_t)row * 128 + kb);
        *(uint4*)(frag + swz(i) * 8) = v;
    }
    __syncthreads();
    int w = tid >> 6, ln = tid & 63;
    int quad = ln >> 4, l15 = ln & 15;
    f32x4 acc[8] = {};
#pragma unroll
    for (int ks = 0; ks < 4; ++ks) {
        bf16x8 af = *(const bf16x8*)(frag + swz((ks * 4 + w) * 64 + ln) * 8);
#pragma unroll
        for (int j = 0; j < 8; ++j) {
            bf16x8 bf = *(const bf16x8*)(Bsw + (((ks * 8 + j) * 64) + ln) * 8);
            acc[j] = __builtin_amdgcn_mfma_f32_16x16x32_bf16(af, bf, acc[j], 0, 0, 0);
        }
    }
#pragma unroll
    for (int j = 0; j < 8; ++j) {
        int col = j * 16 + l15;
#pragma unroll
        for (int r = 0; r < 4; ++r)
            stg[(w * 16 + quad * 4 + r) * STG_STR + col] = f2bf(acc[j][r]);
    }
    __syncthreads();
    for (int i = tid; i < 2048; i += 256) {
        int row = i >> 5, c4 = (i & 31) * 4;
        int grow = m0 + row;
        if (grow >= M) continue;
        ushort4 s4 = *(const ushort4*)(stg + row * STG_STR + c4);
        *(uint2*)(xfb + (size_t)grow * 128 + c4) = *(const uint2*)&s4;
    }
}

// ---------------------------------------------------------------- fused layer (r12 structure)
// t1 = aggb@c2w+c2b; x = ssp(t1)@iw+ib; h += x (bf16 h);
// out = bf16(h@B3) (mid) or bf16(ssp(h@B3+b3)) (last) -> xfb_out.
__global__ __launch_bounds__(256, 4) void fused_layer(
        const unsigned short* __restrict__ aggb,
        const unsigned short* __restrict__ B1sw, const float* __restrict__ b1v,
        const unsigned short* __restrict__ B2sw, const float* __restrict__ b2v,
        const unsigned short* __restrict__ B3sw, const float* __restrict__ b3v,
        unsigned short* __restrict__ hb, unsigned short* __restrict__ xfb_out,
        int M, int last) {
    __shared__ __align__(16) unsigned short frag[8192];         // 16 KB
    __shared__ __align__(16) unsigned short stg[64 * STG_STR];  // 17.5 KB
    int tid = threadIdx.x;
    int m0 = blockIdx.x * 64;

    // stage aggb rows -> swizzled A-frags
    for (int i = tid; i < 1024; i += 256) {
        int ks = i >> 8, w_ = (i >> 6) & 3, ln_ = i & 63;
        int row = m0 + w_ * 16 + (ln_ & 15);
        int kb = ks * 32 + (ln_ >> 4) * 8;
        uint4 v = make_uint4(0, 0, 0, 0);
        if (row < M) v = *(const uint4*)(aggb + (size_t)row * 128 + kb);
        *(uint4*)(frag + swz(i) * 8) = v;
    }
    __syncthreads();

    int w = tid >> 6, ln = tid & 63;
    int quad = ln >> 4, l15 = ln & 15;

    // conv2 MFMA
    f32x4 acc[8] = {};
#pragma unroll
    for (int ks = 0; ks < 4; ++ks) {
        bf16x8 af = *(const bf16x8*)(frag + swz((ks * 4 + w) * 64 + ln) * 8);
#pragma unroll
        for (int j = 0; j < 8; ++j) {
            bf16x8 bf = *(const bf16x8*)(B1sw + (((ks * 8 + j) * 64) + ln) * 8);
            acc[j] = __builtin_amdgcn_mfma_f32_16x16x32_bf16(af, bf, acc[j], 0, 0, 0);
        }
    }

    // repack ssp(t1+b1) -> A-frags (own-wave chunks; intra-wave ds ordering)
#pragma unroll
    for (int j = 0; j < 8; ++j) {
        int col = j * 16 + l15;
        float bv = b1v[col];
        int ks2 = j >> 1;
        int quad2 = (col >> 3) & 3;
        int jj = l15 & 7;
        int cbase = (ks2 * 4 + w) * 64 + quad2 * 16 + quad * 4;
#pragma unroll
        for (int r = 0; r < 4; ++r) {
            float s = sspf(acc[j][r] + bv);
            frag[swz(cbase + r) * 8 + jj] = f2bf(s);
        }
    }

    // int_lin MFMA
    f32x4 acc2[8] = {};
#pragma unroll
    for (int ks = 0; ks < 4; ++ks) {
        bf16x8 af = *(const bf16x8*)(frag + swz((ks * 4 + w) * 64 + ln) * 8);
#pragma unroll
        for (int j = 0; j < 8; ++j) {
            bf16x8 bf = *(const bf16x8*)(B2sw + (((ks * 8 + j) * 64) + ln) * 8);
            acc2[j] = __builtin_amdgcn_mfma_f32_16x16x32_bf16(af, bf, acc2[j], 0, 0, 0);
        }
    }

    // stage x = bf16(acc2 + b2)
#pragma unroll
    for (int j = 0; j < 8; ++j) {
        int col = j * 16 + l15;
        float bv = b2v[col];
#pragma unroll
        for (int r = 0; r < 4; ++r)
            stg[(w * 16 + quad * 4 + r) * STG_STR + col] = f2bf(acc2[j][r] + bv);
    }
    __syncthreads();

    // h += x (bf16 h, fp32 add); write h_new to global + frag LDS
    for (int i = tid; i < 2048; i += 256) {
        int row = i >> 5, c4 = (i & 31) * 4;
        int grow = m0 + row;
        ushort4 xv = *(const ushort4*)(stg + row * STG_STR + c4);
        unsigned short t4[4];
        if (grow < M) {
            unsigned short* hp = hb + (size_t)grow * 128 + c4;
            ushort4 hv = *(const ushort4*)hp;
            t4[0] = f2bf(bf2f(hv.x) + bf2f(xv.x));
            t4[1] = f2bf(bf2f(hv.y) + bf2f(xv.y));
            t4[2] = f2bf(bf2f(hv.z) + bf2f(xv.z));
            t4[3] = f2bf(bf2f(hv.w) + bf2f(xv.w));
            *(uint2*)hp = *(const uint2*)t4;
        } else {
            t4[0] = t4[1] = t4[2] = t4[3] = 0;
        }
        int w_ = row >> 4, l15_ = row & 15;
        int ks = c4 >> 5, q_ = (c4 >> 3) & 3, jj = c4 & 7;
        int c = (ks * 4 + w_) * 64 + q_ * 16 + l15_;
        *(uint2*)(frag + swz(c) * 8 + jj) = *(const uint2*)t4;
    }
    __syncthreads();

    // next conv1 (or lin1) MFMA
    f32x4 acc3[8] = {};
#pragma unroll
    for (int ks = 0; ks < 4; ++ks) {
        bf16x8 af = *(const bf16x8*)(frag + swz((ks * 4 + w) * 64 + ln) * 8);
#pragma unroll
        for (int j = 0; j < 8; ++j) {
            bf16x8 bf = *(const bf16x8*)(B3sw + (((ks * 8 + j) * 64) + ln) * 8);
            acc3[j] = __builtin_amdgcn_mfma_f32_16x16x32_bf16(af, bf, acc3[j], 0, 0, 0);
        }
    }

    // stage output bf16 (ssp in fp32 before rounding on last layer)
#pragma unroll
    for (int j = 0; j < 8; ++j) {
        int col = j * 16 + l15;
        float bv = last ? b3v[col] : 0.f;
#pragma unroll
        for (int r = 0; r < 4; ++r) {
            float v = acc3[j][r] + bv;
            if (last) v = sspf(v);
            stg[(w * 16 + quad * 4 + r) * STG_STR + col] = f2bf(v);
        }
    }
    __syncthreads();

    // write xfb_out (bf16; last layer this is s)
    for (int i = tid; i < 2048; i += 256) {
        int row = i >> 5, c4 = (i & 31) * 4;
        int grow = m0 + row;
        if (grow >= M) continue;
        ushort4 s4 = *(const ushort4*)(stg + row * STG_STR + c4);
        *(uint2*)(xfb_out + (size_t)grow * 128 + c4) = *(const uint2*)&s4;
    }
}

// ---------------------------------------------------------------- atom -> mol sum (bf16 in)
#define MR_ATOMS 32
__global__ __launch_bounds__(128) void mol_reduce(
        const unsigned short* __restrict__ s, const int* __restrict__ a2c,
        const int* __restrict__ c2m, float* __restrict__ mols,
        int* __restrict__ cnt, int N) {
    int f = threadIdx.x;
    int a0 = blockIdx.x * MR_ATOMS;
    int a1 = min(a0 + MR_ATOMS, N);
    float sum = 0.f;
    int cur = -1, run = 0;
    for (int a = a0; a < a1; ++a) {
        int m = c2m[a2c[a]];
        if (m != cur) {
            if (cur >= 0) {
                unsafeAtomicAdd(&mols[(size_t)cur * H_DIM + f], sum);
                if (f == 0) atomicAdd(&cnt[cur], run);
            }
            cur = m; sum = 0.f; run = 0;
        }
        sum += bf2f(s[(size_t)a * H_DIM + f]);
        ++run;
    }
    if (cur >= 0) {
        unsafeAtomicAdd(&mols[(size_t)cur * H_DIM + f], sum);
        if (f == 0) atomicAdd(&cnt[cur], run);
    }
}

// ---------------------------------------------------------------- head
__global__ __launch_bounds__(128) void head_kernel(
        const float* __restrict__ mols, const int* __restrict__ cnt,
        const float* __restrict__ l2w, const float* __restrict__ l2b,
        const float* __restrict__ hw1, const float* __restrict__ hb1,
        const float* __restrict__ hw2, const float* __restrict__ hb2,
        float* __restrict__ out) {
    int m = blockIdx.x, f = threadIdx.x;
    __shared__ float me[H_DIM];
    __shared__ float u[H_DIM / 2];
    const float* ms = mols + (size_t)m * H_DIM;
    float acc = l2b[f] * (float)cnt[m];
#pragma unroll 16
    for (int k = 0; k < H_DIM; ++k) acc += ms[k] * l2w[k * H_DIM + f];
    me[f] = acc;
    __syncthreads();
    if (f < 64) {
        float a2 = hb1[f];
#pragma unroll 16
        for (int k = 0; k < H_DIM; ++k) a2 += me[k] * hw1[k * 64 + f];
        u[f] = sspf(a2);
    }
    __syncthreads();
    if (f == 0) {
        float o = hb2[0];
#pragma unroll 16
        for (int j = 0; j < 64; ++j) o += u[j] * hw2[j];
        out[m] = o;
    }
}

// ---------------------------------------------------------------- launch
extern "C" void kernel_launch(void* const* d_in, const int* in_sizes, int n_in,
                              void* d_out, int out_size, void* d_ws, size_t ws_size,
                              hipStream_t stream) {
    const int*   z   = (const int*)d_in[0];
    const float* pos = (const float*)d_in[1];
    const int*   er  = (const int*)d_in[2];
    const int*   ec  = (const int*)d_in[3];
    const int*   a2c = (const int*)d_in[4];
    const int*   c2m = (const int*)d_in[5];
    const float* emb = (const float*)d_in[6];
    const float* w1  = (const float*)d_in[7];
    const float* b1  = (const float*)d_in[8];
    const float* w2  = (const float*)d_in[9];
    const float* b2  = (const float*)d_in[10];
    const float* c1w = (const float*)d_in[11];
    const float* c2w = (const float*)d_in[12];
    const float* c2b = (const float*)d_in[13];
    const float* iw  = (const float*)d_in[14];
    const float* ib  = (const float*)d_in[15];
    const float* l1w = (const float*)d_in[16];
    const float* l1b = (const float*)d_in[17];
    const float* l2w = (const float*)d_in[18];
    const float* l2b = (const float*)d_in[19];
    const float* hw1 = (const float*)d_in[20];
    const float* hb1 = (const float*)d_in[21];
    const float* hw2 = (const float*)d_in[22];
    const float* hb2 = (const float*)d_in[23];

    const int N  = in_sizes[0];
    const int E  = in_sizes[2];
    const int NM = out_size;
    float* out = (float*)d_out;

    // workspace layout (~70 MB)
    char* wsp = (char*)d_ws;
    uint2* ebuf = (uint2*)wsp;            wsp += (size_t)E * 8;
    unsigned short* tabb = (unsigned short*)wsp;  wsp += (size_t)L_LAYERS * TBL * NF_DIM * 2;
    unsigned short* syb  = (unsigned short*)wsp;  wsp += (size_t)L_LAYERS * TBL * NF_DIM * 2;
    unsigned short* wbt = (unsigned short*)wsp;  wsp += (size_t)25 * 16384 * 2;
    unsigned short* hb  = (unsigned short*)wsp;  wsp += (size_t)N * H_DIM * 2;
    unsigned short* xfb = (unsigned short*)wsp;  wsp += (size_t)N * H_DIM * 2;
    unsigned short* aggb = (unsigned short*)wsp; wsp += (size_t)N * H_DIM * 2;
    float* mols = (float*)wsp;            wsp += (size_t)NM * H_DIM * 4;
    int*   cnt_m = (int*)wsp;             wsp += (size_t)NM * 4;
    int*   ccnt  = (int*)wsp;             wsp += (size_t)N * 4;
    int*   row_start = (int*)wsp;         wsp += (size_t)(N + 1) * 4;
    int*   rank  = (int*)wsp;             wsp += (size_t)E * 4;
    int*   bsums = (int*)wsp;             wsp += 256 * 4;
    int*   excl  = (int*)wsp;

    // --- CSR build (rank-based, atomic-free scatter) ---
    hipMemsetAsync(ccnt, 0, (size_t)N * sizeof(int), stream);
    count_kernel<<<(E + 255) / 256, 256, 0, stream>>>(ec, ccnt, rank, E);
    int nb = (N + SCAN_B - 1) / SCAN_B;
    scan1<<<nb, SCAN_B, 0, stream>>>(ccnt, excl, bsums, N);
    scan2<<<1, SCAN_B, 0, stream>>>(bsums, nb);
    scan3<<<nb, SCAN_B, 0, stream>>>(excl, bsums, row_start, N, E);
    build_edges<<<(E + 255) / 256, 256, 0, stream>>>(
        er, ec, pos, row_start, rank, ebuf, E);

    // --- filter tables: VALU phase then MFMA phase ---
    bt_sy<<<L_LAYERS * (TBL / T_PER), 128, 0, stream>>>(w1, b1, syb);
    embed_kernel<<<(N * H_DIM + 255) / 256, 256, 0, stream>>>(z, emb, hb, N);
    prep_wt_all<<<25, 256, 0, stream>>>(c1w, c2w, iw, l1w, w2, wbt);
    bt_gemm<<<L_LAYERS * (TBL / 64), 256, 0, stream>>>(
        syb, wbt + (size_t)19 * 16384, b2, tabb);

    int gblocks = (N + 63) / 64;
    gemm_l0<<<gblocks, 256, 0, stream>>>(hb, wbt, xfb, N);

    for (int l = 0; l < L_LAYERS; ++l) {
        edge_agg<<<(N + 7) / 8, 256, 0, stream>>>(
            ebuf, row_start, xfb, tabb + (size_t)l * TBL * NF_DIM, aggb, N);
        int last = (l == L_LAYERS - 1);
        const unsigned short* B3 = last ? wbt + (size_t)18 * 16384
                                        : wbt + (size_t)(l + 1) * 16384;
        fused_layer<<<gblocks, 256, 0, stream>>>(
            aggb,
            wbt + (size_t)(6 + l) * 16384,  c2b + (size_t)l * H_DIM,
            wbt + (size_t)(12 + l) * 16384, ib + (size_t)l * H_DIM,
            B3, l1b, hb, xfb, N, last);
    }
    // final s (bf16) is in xfb

    hipMemsetAsync(mols, 0, (size_t)NM * H_DIM * sizeof(float) + NM * sizeof(int), stream);
    mol_reduce<<<(N + MR_ATOMS - 1) / MR_ATOMS, 128, 0, stream>>>(
        xfb, a2c, c2m, mols, cnt_m, N);
    head_kernel<<<NM, 128, 0, stream>>>(mols, cnt_m, l2w, l2b, hw1, hb1, hw2, hb2, out);
}